// Round 11
// baseline (106.565 us; speedup 1.0000x reference)
//
#include <hip/hip_runtime.h>

// Chamfer reconstruction loss, B=16, P=Q=4096, 3-D points, via bf16 MFMA.
// d(i,j) = |q_i|^2 + |t_j|^2 - 2 q_i.t_j; cross term + |t|^2 via one
// v_mfma_f32_32x32x16_bf16 per 32x32 tile (A: a=bf16(-2q) twice + 1.0;
// B: t_hi, t_lo, |t|^2 hi/lo; fp32 accum). Query rounding error is
// per-row-constant -> cancels in argmin, averages out in the mean.
//
// R11: R10 bit-identical EXCEPT the min reduction is plain fminf trees
// instead of 64 pinned inline-asm v_min3 per iteration. The asm blocks
// were un-reorderable walls: the scheduler couldn't software-pipeline
// MFMA results into the VALU min chain or hoist ds_reads across them.
// fminf(fminf(,),) pattern-matches to v_min3_f32 with full freedom.

#define NB 16
#define NP 4096
#define THREADS 256
#define INV128 0.0078125f   // gt normalize: c/128 - 1
#define FINF __int_as_float(0x7F800000)

typedef __attribute__((ext_vector_type(8)))  short bf16x8;
typedef __attribute__((ext_vector_type(16))) float f32x16;

__device__ __forceinline__ short bf16rne(float f) {
    unsigned u = __float_as_uint(f);
    return (short)((u + 0x7FFFu + ((u >> 16) & 1u)) >> 16);
}
__device__ __forceinline__ float bf2f(short s) {
    return __uint_as_float(((unsigned)(unsigned short)s) << 16);
}

// grid = 512: dir = bid>>8, b = (bid>>4)&15, qpair = bid&15.
// Block covers qblks {2*qpair, 2*qpair+1} (128 queries each, R5/R9 geometry).
__global__ __launch_bounds__(THREADS) void chamfer_kernel(const float* __restrict__ gen,
                                                          const float* __restrict__ label,
                                                          float* __restrict__ out) {
    // 64KB pack + zero line + prefetch-overrun pad (R9 layout, verbatim)
    __shared__ short spack[NP * 8 + 1280];
    __shared__ float wpart[8];

    const int bid   = blockIdx.x;
    const int dir   = bid >> 8;
    const int b     = (bid >> 4) & 15;
    const int qpair = bid & 15;
    const int tid   = threadIdx.x;
    const int lane  = tid & 63;
    const int wave  = tid >> 6;           // 0..3
    const int base  = b * NP;

    if (tid < 8) spack[NP * 8 + tid] = 0;   // zero line for high-half lanes

    // ---- pack 4096 targets: [t_hi xyz, t_lo xyz, t2_hi, t2_lo] bf16x8 ----
    #pragma unroll 4
    for (int k = 0; k < 16; ++k) {
        int j = tid + k * 256;
        float x, y, z;
        if (dir == 0) {                       // targets = normalized gt
            const float* row = label + (size_t)(base + j) * 5;
            x = fmaf(row[1], INV128, -1.0f);
            y = fmaf(row[2], INV128, -1.0f);
            z = fmaf(row[3], INV128, -1.0f);
        } else {                              // targets = raw gen
            const float* g = gen + (size_t)(base + j) * 3;
            x = g[0]; y = g[1]; z = g[2];
        }
        float t2 = fmaf(x, x, fmaf(y, y, z * z));
        short xh = bf16rne(x), yh = bf16rne(y), zh = bf16rne(z);
        short xl = bf16rne(x - bf2f(xh));
        short yl = bf16rne(y - bf2f(yh));
        short zl = bf16rne(z - bf2f(zh));
        short th = bf16rne(t2);
        short tl = bf16rne(t2 - bf2f(th));
        bf16x8 v = {xh, yh, zh, xl, yl, zl, th, tl};
        *(bf16x8*)(spack + j * 8) = v;
    }
    __syncthreads();                          // spack is read-only from here on

    float sacc = 0.0f;                        // per-thread sum over both qblks
    const f32x16 zc = {};

    #pragma unroll 1
    for (int sub = 0; sub < 2; ++sub) {
        const int qblk = qpair * 2 + sub;

        // ---- per-lane query fragment: rows = lane&31, k8-15 zero ----
        const int qrow = base + qblk * 128 + wave * 32 + (lane & 31);
        float q2 = 0.0f;
        bf16x8 afrag = (bf16x8)(short)0;
        if (lane < 32) {
            float x, y, z;
            if (dir == 0) {                   // queries = raw gen
                const float* g = gen + (size_t)qrow * 3;
                x = g[0]; y = g[1]; z = g[2];
            } else {                          // queries = normalized gt
                const float* row = label + (size_t)qrow * 5;
                x = fmaf(row[1], INV128, -1.0f);
                y = fmaf(row[2], INV128, -1.0f);
                z = fmaf(row[3], INV128, -1.0f);
            }
            q2 = fmaf(x, x, fmaf(y, y, z * z));  // exact fp32, added after min
            short ax = bf16rne(-2.0f * x), ay = bf16rne(-2.0f * y), az = bf16rne(-2.0f * z);
            const short one = 0x3F80;         // bf16 1.0
            bf16x8 a = {ax, ay, az, ax, ay, az, one, one};
            afrag = a;
        }

        float mn[16];
        #pragma unroll
        for (int r = 0; r < 16; ++r) mn[r] = FINF;

        // ---- stream 128 col-tiles, 4/iter, register double-buffered ----
        const short* zl = spack + NP * 8;
        const short* p0 = (lane < 32) ? (spack + (lane & 31) * 8)       : zl;
        const short* p1 = (lane < 32) ? (spack + (lane & 31) * 8 + 256) : zl;
        const short* p2 = (lane < 32) ? (spack + (lane & 31) * 8 + 512) : zl;
        const short* p3 = (lane < 32) ? (spack + (lane & 31) * 8 + 768) : zl;
        const int step = (lane < 32) ? 1024 : 0;   // 4 tiles = 128 cols * 8 shorts

        bf16x8 b0 = *(const bf16x8*)p0;
        bf16x8 b1 = *(const bf16x8*)p1;
        bf16x8 b2 = *(const bf16x8*)p2;
        bf16x8 b3 = *(const bf16x8*)p3;
        #pragma unroll 2
        for (int it = 0; it < 32; ++it) {
            p0 += step; p1 += step; p2 += step; p3 += step;
            bf16x8 n0 = *(const bf16x8*)p0;   // last iter: dead reads into pad
            bf16x8 n1 = *(const bf16x8*)p1;
            bf16x8 n2 = *(const bf16x8*)p2;
            bf16x8 n3 = *(const bf16x8*)p3;
            f32x16 c0 = __builtin_amdgcn_mfma_f32_32x32x16_bf16(afrag, b0, zc, 0, 0, 0);
            f32x16 c1 = __builtin_amdgcn_mfma_f32_32x32x16_bf16(afrag, b1, zc, 0, 0, 0);
            f32x16 c2 = __builtin_amdgcn_mfma_f32_32x32x16_bf16(afrag, b2, zc, 0, 0, 0);
            f32x16 c3 = __builtin_amdgcn_mfma_f32_32x32x16_bf16(afrag, b3, zc, 0, 0, 0);
            #pragma unroll
            for (int r = 0; r < 16; ++r) {
                // fmin trees -> v_min3_f32 via pattern match, scheduler-free
                float m01 = fminf(c0[r], c1[r]);
                float m23 = fminf(c2[r], c3[r]);
                mn[r] = fminf(fminf(m01, m23), mn[r]);
            }
            b0 = n0; b1 = n1; b2 = n2; b3 = n3;
        }

        // ---- fold 32 column-classes (butterfly within each 32-lane half) ----
        #pragma unroll
        for (int m = 1; m <= 16; m <<= 1) {
            #pragma unroll
            for (int r = 0; r < 16; ++r)
                mn[r] = fminf(mn[r], __shfl_xor(mn[r], m, 64));
        }

        // ---- d(row) = mn + |q_row|^2 ; sum this half's 16 rows ----
        // C/D layout: row = (r&3) + 8*(r>>2) + 4*(lane>>5), col = lane&31.
        const int h4 = (lane >> 5) * 4;
        #pragma unroll
        for (int r = 0; r < 16; ++r) {
            int row = (r & 3) + 8 * (r >> 2) + h4;
            sacc += mn[r] + __shfl(q2, row, 64);  // q2 lives at lane==row (low half)
        }
    }

    // ---- single-dispatch finalization: one device-scope atomicAdd/block ----
    if ((lane & 31) == 0) wpart[wave * 2 + (lane >> 5)] = sacc;
    __syncthreads();
    if (tid == 0) {
        float t = 0.0f;
        #pragma unroll
        for (int i = 0; i < 8; ++i) t += wpart[i];
        atomicAdd(out, t * (1.0f / 65536.0f));
    }
}

extern "C" void kernel_launch(void* const* d_in, const int* in_sizes, int n_in,
                              void* d_out, int out_size, void* d_ws, size_t ws_size,
                              hipStream_t stream) {
    const float* gen   = (const float*)d_in[0];   // [B*P, 3] fp32
    // d_in[1] = batch_gen (int32) — unused: segments are contiguous equal-size
    const float* label = (const float*)d_in[2];   // [B*Q, 5] fp32
    float* out = (float*)d_out;

    // timed replays re-poison d_out to 0xAA — zero it in-stream before accumulating
    hipMemsetAsync(out, 0, sizeof(float), stream);
    chamfer_kernel<<<512, THREADS, 0, stream>>>(gen, label, out);
}

// Round 12
// 93.255 us; speedup vs baseline: 1.1427x; 1.1427x over previous
//
#include <hip/hip_runtime.h>

// Chamfer reconstruction loss, B=16, P=Q=4096, 3-D points, via bf16 MFMA.
// d(i,j) = |q_i|^2 + |t_j|^2 - 2 q_i.t_j; cross term + |t|^2 via one
// v_mfma_f32_32x32x16_bf16 per 32x32 tile (A: a=bf16(-2q) twice + 1.0;
// B: t_hi, t_lo, |t|^2 hi/lo; fp32 accum). Query rounding error is
// per-row-constant -> cancels in argmin, averages out in the mean.
//
// R12: revert R11's fminf regression (IEEE-NaN lowering doubled the VALU
// stream; asm v_min3 is the fast form). On top of R10: FUSE the two
// query-sub-blocks into one streaming pass — two A-fragments and two
// min-accumulator sets stay resident, each B tile is loaded ONCE and fed
// to 2 MFMAs. Halves ds_read_b128 count (256->128/wave), the dominant
// per-CU pipe cost. Geometry (512 blocks / 256 thr / 64KB pack) untouched.

#define NB 16
#define NP 4096
#define THREADS 256
#define INV128 0.0078125f   // gt normalize: c/128 - 1
#define FINF __int_as_float(0x7F800000)

typedef __attribute__((ext_vector_type(8)))  short bf16x8;
typedef __attribute__((ext_vector_type(16))) float f32x16;

__device__ __forceinline__ short bf16rne(float f) {
    unsigned u = __float_as_uint(f);
    return (short)((u + 0x7FFFu + ((u >> 16) & 1u)) >> 16);
}
__device__ __forceinline__ float bf2f(short s) {
    return __uint_as_float(((unsigned)(unsigned short)s) << 16);
}

// grid = 512: dir = bid>>8, b = (bid>>4)&15, qpair = bid&15.
// Block covers qblks {2*qpair, 2*qpair+1} (128 queries each, R5/R9 geometry).
__global__ __launch_bounds__(THREADS) void chamfer_kernel(const float* __restrict__ gen,
                                                          const float* __restrict__ label,
                                                          float* __restrict__ out) {
    // 64KB pack + zero line + prefetch-overrun pad (R9 layout, verbatim)
    __shared__ short spack[NP * 8 + 1280];
    __shared__ float wpart[8];

    const int bid   = blockIdx.x;
    const int dir   = bid >> 8;
    const int b     = (bid >> 4) & 15;
    const int qpair = bid & 15;
    const int tid   = threadIdx.x;
    const int lane  = tid & 63;
    const int wave  = tid >> 6;           // 0..3
    const int base  = b * NP;

    if (tid < 8) spack[NP * 8 + tid] = 0;   // zero line for high-half lanes

    // ---- pack 4096 targets: [t_hi xyz, t_lo xyz, t2_hi, t2_lo] bf16x8 ----
    #pragma unroll 4
    for (int k = 0; k < 16; ++k) {
        int j = tid + k * 256;
        float x, y, z;
        if (dir == 0) {                       // targets = normalized gt
            const float* row = label + (size_t)(base + j) * 5;
            x = fmaf(row[1], INV128, -1.0f);
            y = fmaf(row[2], INV128, -1.0f);
            z = fmaf(row[3], INV128, -1.0f);
        } else {                              // targets = raw gen
            const float* g = gen + (size_t)(base + j) * 3;
            x = g[0]; y = g[1]; z = g[2];
        }
        float t2 = fmaf(x, x, fmaf(y, y, z * z));
        short xh = bf16rne(x), yh = bf16rne(y), zh = bf16rne(z);
        short xl = bf16rne(x - bf2f(xh));
        short yl = bf16rne(y - bf2f(yh));
        short zl = bf16rne(z - bf2f(zh));
        short th = bf16rne(t2);
        short tl = bf16rne(t2 - bf2f(th));
        bf16x8 v = {xh, yh, zh, xl, yl, zl, th, tl};
        *(bf16x8*)(spack + j * 8) = v;
    }
    __syncthreads();                          // spack is read-only from here on

    // ---- two per-lane query fragments (sub 0 / sub 1): rows = lane&31 ----
    float q2a = 0.0f, q2b = 0.0f;
    bf16x8 af0 = (bf16x8)(short)0, af1 = (bf16x8)(short)0;
    #pragma unroll
    for (int sub = 0; sub < 2; ++sub) {
        const int qblk = qpair * 2 + sub;
        const int qrow = base + qblk * 128 + wave * 32 + (lane & 31);
        if (lane < 32) {
            float x, y, z;
            if (dir == 0) {                   // queries = raw gen
                const float* g = gen + (size_t)qrow * 3;
                x = g[0]; y = g[1]; z = g[2];
            } else {                          // queries = normalized gt
                const float* row = label + (size_t)qrow * 5;
                x = fmaf(row[1], INV128, -1.0f);
                y = fmaf(row[2], INV128, -1.0f);
                z = fmaf(row[3], INV128, -1.0f);
            }
            float q2 = fmaf(x, x, fmaf(y, y, z * z));  // exact fp32, post-min
            short ax = bf16rne(-2.0f * x), ay = bf16rne(-2.0f * y), az = bf16rne(-2.0f * z);
            const short one = 0x3F80;         // bf16 1.0
            bf16x8 a = {ax, ay, az, ax, ay, az, one, one};
            if (sub == 0) { af0 = a; q2a = q2; }
            else          { af1 = a; q2b = q2; }
        }
    }

    float mna[16], mnb[16];
    #pragma unroll
    for (int r = 0; r < 16; ++r) { mna[r] = FINF; mnb[r] = FINF; }
    const f32x16 zc = {};

    // ---- stream 128 col-tiles once, 4/iter, B shared by both A-frags ----
    const short* zl = spack + NP * 8;
    const short* p0 = (lane < 32) ? (spack + (lane & 31) * 8)       : zl;
    const short* p1 = (lane < 32) ? (spack + (lane & 31) * 8 + 256) : zl;
    const short* p2 = (lane < 32) ? (spack + (lane & 31) * 8 + 512) : zl;
    const short* p3 = (lane < 32) ? (spack + (lane & 31) * 8 + 768) : zl;
    const int step = (lane < 32) ? 1024 : 0;  // 4 tiles = 128 cols * 8 shorts

    bf16x8 b0 = *(const bf16x8*)p0;
    bf16x8 b1 = *(const bf16x8*)p1;
    bf16x8 b2 = *(const bf16x8*)p2;
    bf16x8 b3 = *(const bf16x8*)p3;
    #pragma unroll 2
    for (int it = 0; it < 32; ++it) {
        p0 += step; p1 += step; p2 += step; p3 += step;
        bf16x8 n0 = *(const bf16x8*)p0;       // last iter: dead reads into pad
        bf16x8 n1 = *(const bf16x8*)p1;
        bf16x8 n2 = *(const bf16x8*)p2;
        bf16x8 n3 = *(const bf16x8*)p3;
        f32x16 c0a = __builtin_amdgcn_mfma_f32_32x32x16_bf16(af0, b0, zc, 0, 0, 0);
        f32x16 c1a = __builtin_amdgcn_mfma_f32_32x32x16_bf16(af0, b1, zc, 0, 0, 0);
        f32x16 c2a = __builtin_amdgcn_mfma_f32_32x32x16_bf16(af0, b2, zc, 0, 0, 0);
        f32x16 c3a = __builtin_amdgcn_mfma_f32_32x32x16_bf16(af0, b3, zc, 0, 0, 0);
        #pragma unroll
        for (int r = 0; r < 16; ++r) {
            asm("v_min3_f32 %0, %1, %2, %0" : "+v"(mna[r]) : "v"(c0a[r]), "v"(c1a[r]));
            asm("v_min3_f32 %0, %1, %2, %0" : "+v"(mna[r]) : "v"(c2a[r]), "v"(c3a[r]));
        }
        f32x16 c0b = __builtin_amdgcn_mfma_f32_32x32x16_bf16(af1, b0, zc, 0, 0, 0);
        f32x16 c1b = __builtin_amdgcn_mfma_f32_32x32x16_bf16(af1, b1, zc, 0, 0, 0);
        f32x16 c2b = __builtin_amdgcn_mfma_f32_32x32x16_bf16(af1, b2, zc, 0, 0, 0);
        f32x16 c3b = __builtin_amdgcn_mfma_f32_32x32x16_bf16(af1, b3, zc, 0, 0, 0);
        #pragma unroll
        for (int r = 0; r < 16; ++r) {
            asm("v_min3_f32 %0, %1, %2, %0" : "+v"(mnb[r]) : "v"(c0b[r]), "v"(c1b[r]));
            asm("v_min3_f32 %0, %1, %2, %0" : "+v"(mnb[r]) : "v"(c2b[r]), "v"(c3b[r]));
        }
        b0 = n0; b1 = n1; b2 = n2; b3 = n3;
    }

    // ---- fold 32 column-classes per sub (butterfly in each 32-lane half) ----
    float sacc = 0.0f;
    const int h4 = (lane >> 5) * 4;
    #pragma unroll
    for (int m = 1; m <= 16; m <<= 1) {
        #pragma unroll
        for (int r = 0; r < 16; ++r)
            mna[r] = fminf(mna[r], __shfl_xor(mna[r], m, 64));
    }
    #pragma unroll
    for (int r = 0; r < 16; ++r) {
        // C/D layout: row = (r&3) + 8*(r>>2) + 4*(lane>>5), col = lane&31.
        int row = (r & 3) + 8 * (r >> 2) + h4;
        sacc += mna[r] + __shfl(q2a, row, 64);   // q2 lives at lane==row (low half)
    }
    #pragma unroll
    for (int m = 1; m <= 16; m <<= 1) {
        #pragma unroll
        for (int r = 0; r < 16; ++r)
            mnb[r] = fminf(mnb[r], __shfl_xor(mnb[r], m, 64));
    }
    #pragma unroll
    for (int r = 0; r < 16; ++r) {
        int row = (r & 3) + 8 * (r >> 2) + h4;
        sacc += mnb[r] + __shfl(q2b, row, 64);
    }

    // ---- single-dispatch finalization: one device-scope atomicAdd/block ----
    if ((lane & 31) == 0) wpart[wave * 2 + (lane >> 5)] = sacc;
    __syncthreads();
    if (tid == 0) {
        float t = 0.0f;
        #pragma unroll
        for (int i = 0; i < 8; ++i) t += wpart[i];
        atomicAdd(out, t * (1.0f / 65536.0f));
    }
}

extern "C" void kernel_launch(void* const* d_in, const int* in_sizes, int n_in,
                              void* d_out, int out_size, void* d_ws, size_t ws_size,
                              hipStream_t stream) {
    const float* gen   = (const float*)d_in[0];   // [B*P, 3] fp32
    // d_in[1] = batch_gen (int32) — unused: segments are contiguous equal-size
    const float* label = (const float*)d_in[2];   // [B*Q, 5] fp32
    float* out = (float*)d_out;

    // timed replays re-poison d_out to 0xAA — zero it in-stream before accumulating
    hipMemsetAsync(out, 0, sizeof(float), stream);
    chamfer_kernel<<<512, THREADS, 0, stream>>>(gen, label, out);
}

// Round 13
// 91.041 us; speedup vs baseline: 1.1705x; 1.0243x over previous
//
#include <hip/hip_runtime.h>

// Chamfer reconstruction loss, B=16, P=Q=4096, 3-D points, via bf16 MFMA.
// d(i,j) = |q_i|^2 + |t_j|^2 - 2 q_i.t_j; cross term + |t|^2 via one
// v_mfma_f32_32x32x16_bf16 per 32x32 tile (A: a=bf16(-2q) twice + 1.0;
// B: t_hi, t_lo, |t|^2 hi/lo; fp32 accum). Query rounding error is
// per-row-constant -> cancels in argmin, averages out in the mean.
//
// R13 (final): R12's fused chamfer body (fastest: 40.4 us — B tiles loaded
// once, fed to both A-fragments) + R9's finalization (cheapest in graph
// total: plain partial store + tiny reduce dispatch, no memset node).
// Session A/B: partials+reduce (R9, 89.8 total) beats memset+atomicAdd
// (R10/R12, 92.3/93.3) by ~3 us of graph overhead.
// Chamfer itself sits at a ~27us dispatch/DVFS floor: R10/R12 halved the
// dominant LDS pipe with zero duration change; no pipe >60% busy.

#define NB 16
#define NP 4096
#define THREADS 256
#define INV128 0.0078125f   // gt normalize: c/128 - 1
#define FINF __int_as_float(0x7F800000)

typedef __attribute__((ext_vector_type(8)))  short bf16x8;
typedef __attribute__((ext_vector_type(16))) float f32x16;

__device__ __forceinline__ short bf16rne(float f) {
    unsigned u = __float_as_uint(f);
    return (short)((u + 0x7FFFu + ((u >> 16) & 1u)) >> 16);
}
__device__ __forceinline__ float bf2f(short s) {
    return __uint_as_float(((unsigned)(unsigned short)s) << 16);
}

// grid = 512: dir = bid>>8, b = (bid>>4)&15, qpair = bid&15.
// Block covers qblks {2*qpair, 2*qpair+1} (128 queries each, R5/R9 geometry).
__global__ __launch_bounds__(THREADS) void chamfer_kernel(const float* __restrict__ gen,
                                                          const float* __restrict__ label,
                                                          float* __restrict__ partial) {
    // 64KB pack + zero line + prefetch-overrun pad (R9 layout, verbatim)
    __shared__ short spack[NP * 8 + 1280];
    __shared__ float wpart[8];

    const int bid   = blockIdx.x;
    const int dir   = bid >> 8;
    const int b     = (bid >> 4) & 15;
    const int qpair = bid & 15;
    const int tid   = threadIdx.x;
    const int lane  = tid & 63;
    const int wave  = tid >> 6;           // 0..3
    const int base  = b * NP;

    if (tid < 8) spack[NP * 8 + tid] = 0;   // zero line for high-half lanes

    // ---- pack 4096 targets: [t_hi xyz, t_lo xyz, t2_hi, t2_lo] bf16x8 ----
    #pragma unroll 4
    for (int k = 0; k < 16; ++k) {
        int j = tid + k * 256;
        float x, y, z;
        if (dir == 0) {                       // targets = normalized gt
            const float* row = label + (size_t)(base + j) * 5;
            x = fmaf(row[1], INV128, -1.0f);
            y = fmaf(row[2], INV128, -1.0f);
            z = fmaf(row[3], INV128, -1.0f);
        } else {                              // targets = raw gen
            const float* g = gen + (size_t)(base + j) * 3;
            x = g[0]; y = g[1]; z = g[2];
        }
        float t2 = fmaf(x, x, fmaf(y, y, z * z));
        short xh = bf16rne(x), yh = bf16rne(y), zh = bf16rne(z);
        short xl = bf16rne(x - bf2f(xh));
        short yl = bf16rne(y - bf2f(yh));
        short zl = bf16rne(z - bf2f(zh));
        short th = bf16rne(t2);
        short tl = bf16rne(t2 - bf2f(th));
        bf16x8 v = {xh, yh, zh, xl, yl, zl, th, tl};
        *(bf16x8*)(spack + j * 8) = v;
    }
    __syncthreads();                          // spack is read-only from here on

    // ---- two per-lane query fragments (sub 0 / sub 1): rows = lane&31 ----
    float q2a = 0.0f, q2b = 0.0f;
    bf16x8 af0 = (bf16x8)(short)0, af1 = (bf16x8)(short)0;
    #pragma unroll
    for (int sub = 0; sub < 2; ++sub) {
        const int qblk = qpair * 2 + sub;
        const int qrow = base + qblk * 128 + wave * 32 + (lane & 31);
        if (lane < 32) {
            float x, y, z;
            if (dir == 0) {                   // queries = raw gen
                const float* g = gen + (size_t)qrow * 3;
                x = g[0]; y = g[1]; z = g[2];
            } else {                          // queries = normalized gt
                const float* row = label + (size_t)qrow * 5;
                x = fmaf(row[1], INV128, -1.0f);
                y = fmaf(row[2], INV128, -1.0f);
                z = fmaf(row[3], INV128, -1.0f);
            }
            float q2 = fmaf(x, x, fmaf(y, y, z * z));  // exact fp32, post-min
            short ax = bf16rne(-2.0f * x), ay = bf16rne(-2.0f * y), az = bf16rne(-2.0f * z);
            const short one = 0x3F80;         // bf16 1.0
            bf16x8 a = {ax, ay, az, ax, ay, az, one, one};
            if (sub == 0) { af0 = a; q2a = q2; }
            else          { af1 = a; q2b = q2; }
        }
    }

    float mna[16], mnb[16];
    #pragma unroll
    for (int r = 0; r < 16; ++r) { mna[r] = FINF; mnb[r] = FINF; }
    const f32x16 zc = {};

    // ---- stream 128 col-tiles once, 4/iter, B shared by both A-frags ----
    const short* zl = spack + NP * 8;
    const short* p0 = (lane < 32) ? (spack + (lane & 31) * 8)       : zl;
    const short* p1 = (lane < 32) ? (spack + (lane & 31) * 8 + 256) : zl;
    const short* p2 = (lane < 32) ? (spack + (lane & 31) * 8 + 512) : zl;
    const short* p3 = (lane < 32) ? (spack + (lane & 31) * 8 + 768) : zl;
    const int step = (lane < 32) ? 1024 : 0;  // 4 tiles = 128 cols * 8 shorts

    bf16x8 b0 = *(const bf16x8*)p0;
    bf16x8 b1 = *(const bf16x8*)p1;
    bf16x8 b2 = *(const bf16x8*)p2;
    bf16x8 b3 = *(const bf16x8*)p3;
    #pragma unroll 2
    for (int it = 0; it < 32; ++it) {
        p0 += step; p1 += step; p2 += step; p3 += step;
        bf16x8 n0 = *(const bf16x8*)p0;       // last iter: dead reads into pad
        bf16x8 n1 = *(const bf16x8*)p1;
        bf16x8 n2 = *(const bf16x8*)p2;
        bf16x8 n3 = *(const bf16x8*)p3;
        f32x16 c0a = __builtin_amdgcn_mfma_f32_32x32x16_bf16(af0, b0, zc, 0, 0, 0);
        f32x16 c1a = __builtin_amdgcn_mfma_f32_32x32x16_bf16(af0, b1, zc, 0, 0, 0);
        f32x16 c2a = __builtin_amdgcn_mfma_f32_32x32x16_bf16(af0, b2, zc, 0, 0, 0);
        f32x16 c3a = __builtin_amdgcn_mfma_f32_32x32x16_bf16(af0, b3, zc, 0, 0, 0);
        #pragma unroll
        for (int r = 0; r < 16; ++r) {
            asm("v_min3_f32 %0, %1, %2, %0" : "+v"(mna[r]) : "v"(c0a[r]), "v"(c1a[r]));
            asm("v_min3_f32 %0, %1, %2, %0" : "+v"(mna[r]) : "v"(c2a[r]), "v"(c3a[r]));
        }
        f32x16 c0b = __builtin_amdgcn_mfma_f32_32x32x16_bf16(af1, b0, zc, 0, 0, 0);
        f32x16 c1b = __builtin_amdgcn_mfma_f32_32x32x16_bf16(af1, b1, zc, 0, 0, 0);
        f32x16 c2b = __builtin_amdgcn_mfma_f32_32x32x16_bf16(af1, b2, zc, 0, 0, 0);
        f32x16 c3b = __builtin_amdgcn_mfma_f32_32x32x16_bf16(af1, b3, zc, 0, 0, 0);
        #pragma unroll
        for (int r = 0; r < 16; ++r) {
            asm("v_min3_f32 %0, %1, %2, %0" : "+v"(mnb[r]) : "v"(c0b[r]), "v"(c1b[r]));
            asm("v_min3_f32 %0, %1, %2, %0" : "+v"(mnb[r]) : "v"(c2b[r]), "v"(c3b[r]));
        }
        b0 = n0; b1 = n1; b2 = n2; b3 = n3;
    }

    // ---- fold 32 column-classes per sub (butterfly in each 32-lane half) ----
    float sacc = 0.0f;
    const int h4 = (lane >> 5) * 4;
    #pragma unroll
    for (int m = 1; m <= 16; m <<= 1) {
        #pragma unroll
        for (int r = 0; r < 16; ++r)
            mna[r] = fminf(mna[r], __shfl_xor(mna[r], m, 64));
    }
    #pragma unroll
    for (int r = 0; r < 16; ++r) {
        // C/D layout: row = (r&3) + 8*(r>>2) + 4*(lane>>5), col = lane&31.
        int row = (r & 3) + 8 * (r >> 2) + h4;
        sacc += mna[r] + __shfl(q2a, row, 64);   // q2 lives at lane==row (low half)
    }
    #pragma unroll
    for (int m = 1; m <= 16; m <<= 1) {
        #pragma unroll
        for (int r = 0; r < 16; ++r)
            mnb[r] = fminf(mnb[r], __shfl_xor(mnb[r], m, 64));
    }
    #pragma unroll
    for (int r = 0; r < 16; ++r) {
        int row = (r & 3) + 8 * (r >> 2) + h4;
        sacc += mnb[r] + __shfl(q2b, row, 64);
    }

    // ---- epilogue: plain partial store (R9 finalization) ----
    if ((lane & 31) == 0) wpart[wave * 2 + (lane >> 5)] = sacc;
    __syncthreads();
    if (tid == 0) {
        float t = 0.0f;
        #pragma unroll
        for (int i = 0; i < 8; ++i) t += wpart[i];
        partial[bid] = t;                     // plain store, no init needed
    }
}

__global__ __launch_bounds__(256) void reduce_kernel(const float* __restrict__ partial,
                                                     float* __restrict__ out) {
    int i = threadIdx.x;
    float s = partial[i] + partial[i + 256];  // 512 block partials
    #pragma unroll
    for (int off = 32; off > 0; off >>= 1) s += __shfl_down(s, off, 64);
    __shared__ float ws4[4];
    if ((i & 63) == 0) ws4[i >> 6] = s;
    __syncthreads();
    if (i == 0) out[0] = ((ws4[0] + ws4[1]) + (ws4[2] + ws4[3])) * (1.0f / 65536.0f);
}

extern "C" void kernel_launch(void* const* d_in, const int* in_sizes, int n_in,
                              void* d_out, int out_size, void* d_ws, size_t ws_size,
                              hipStream_t stream) {
    const float* gen   = (const float*)d_in[0];   // [B*P, 3] fp32
    // d_in[1] = batch_gen (int32) — unused: segments are contiguous equal-size
    const float* label = (const float*)d_in[2];   // [B*Q, 5] fp32
    float* partial = (float*)d_ws;                // 512 floats = 2 KB
    float* out = (float*)d_out;

    chamfer_kernel<<<512, THREADS, 0, stream>>>(gen, label, partial);
    reduce_kernel<<<1, 256, 0, stream>>>(partial, out);
}